// Round 7
// baseline (67.886 us; speedup 1.0000x reference)
//
#include <hip/hip_runtime.h>
#include <math.h>

// DRR via Siddon ray tracing, 256^3 volume, 256x256 detector.
// 16 threads cooperate per ray, each owning 1/16 of [amin, amax].
// Lane->ray mapping puts the detector axis with the smallest stride-weighted
// volume motion on the fast (lane) index. Depth-2 software pipeline keeps two
// volume loads in flight. Cells derived per-segment via midpoint-trunc
// (bit-faithful to the reference's rounding). Plane-advance drops range
// checks: out-of-range plane alphas exceed amax by >= one alpha-quantum,
// so they can never win the 3-way merge before the slice ends.

#define NPLANE 256
constexpr int TPR = 16;

// alpha of plane i (float index): (i*sp - src) * (1/sdd)
__device__ __forceinline__ float palpha_f(float fi, float sp, float nsrc, float rd) {
    return fmaf(fi, sp, nsrc) * rd;
}
__device__ __forceinline__ float palpha(int i, float sp, float src, float rd) {
    return fmaf((float)i, sp, -src) * rd;
}

template<bool UNIT>
__device__ __forceinline__ float trace_slice(
    const float* __restrict__ vol,
    float cur, float end, float amax,
    float fix, float fiy, float fiz,
    float dfx, float dfy, float dfz,
    float nxx, float nxy, float nxz,
    float spx, float spy, float spz,
    float nsx, float nsy, float nsz,
    float rdx, float rdy, float rdz,
    float sdx, float sdy, float sdz,
    float sx,  float sy,  float sz,
    float ispx, float ispy, float ispz)
{
    float acc = 0.f;

    #define ADV()                                                              \
        if (nxx == cur) { fix += dfx; nxx = palpha_f(fix, spx, nsx, rdx); }    \
        if (nxy == cur) { fiy += dfy; nxy = palpha_f(fiy, spy, nsy, rdy); }    \
        if (nxz == cur) { fiz += dfz; nxz = palpha_f(fiz, spz, nsz, rdz); }

    #define SEG(CUR, E, ADDR)                                                  \
    {                                                                          \
        float amid = 0.5f * ((CUR) + (E));                                     \
        float pxv = fmaf(amid, sdx, sx);                                       \
        float pyv = fmaf(amid, sdy, sy);                                       \
        float pzv = fmaf(amid, sdz, sz);                                       \
        if (!UNIT) { pxv *= ispx; pyv *= ispy; pzv *= ispz; }                  \
        int jx = (int)pxv; jx = jx < 0 ? 0 : (jx > 255 ? 255 : jx);            \
        int jy = (int)pyv; jy = jy < 0 ? 0 : (jy > 255 ? 255 : jy);            \
        int jz = (int)pzv; jz = jz < 0 ? 0 : (jz > 255 ? 255 : jz);            \
        ADDR = (jx << 16) + (jy << 8) + jz;                                    \
    }

    if (cur < end) {
        ADV();
        float nxt = fminf(fminf(nxx, nxy), nxz);
        float e   = fminf(nxt, amax);
        int a0; SEG(cur, e, a0)
        float s0 = e - cur;
        float v0 = vol[a0];
        cur = nxt;

        if (cur < end) {
            ADV();
            nxt = fminf(fminf(nxx, nxy), nxz);
            e   = fminf(nxt, amax);
            int a1; SEG(cur, e, a1)
            float s1 = e - cur;
            float v1 = vol[a1];
            cur = nxt;

            while (cur < end) {
                ADV();
                nxt = fminf(fminf(nxx, nxy), nxz);
                e   = fminf(nxt, amax);
                int a2; SEG(cur, e, a2)
                float v2 = vol[a2];          // two loads now in flight
                acc = fmaf(v0, s0, acc);     // consume oldest (vmcnt(2))
                v0 = v1; s0 = s1;
                v1 = v2; s1 = e - cur;
                cur = nxt;
            }
            acc = fmaf(v0, s0, acc);
            acc = fmaf(v1, s1, acc);
        } else {
            acc = fmaf(v0, s0, acc);
        }
    }
    #undef ADV
    #undef SEG
    return acc;
}

__global__ __launch_bounds__(256) void drr_kernel(
    const float* __restrict__ vol,
    const float* __restrict__ spacing,
    const float* __restrict__ sdrp,
    const float* __restrict__ rot,
    const float* __restrict__ trans,
    float* __restrict__ out)
{
    int gid  = blockIdx.x * blockDim.x + threadIdx.x;
    int part = gid & (TPR - 1);
    int rl   = gid / TPR;

    float theta = rot[0], phi = rot[1], gam = rot[2];
    float ct = cosf(theta), st = sinf(theta);
    float cp = cosf(phi),   sp_ = sinf(phi);
    float cg = cosf(gam),   sg = sinf(gam);

    float r0x = ct * cp, r0y = st * cp, r0z = -sp_;
    float ux = ct * sp_ * sg - st * cg, uy = st * sp_ * sg + ct * cg, uz = cp * sg;
    float vx = ct * sp_ * cg + st * sg, vy = st * sp_ * cg - ct * sg, vz = cp * cg;

    // lane-fast detector axis = least stride-weighted volume motion (uniform)
    float cost_u = fabsf(ux) * 65536.f + fabsf(uy) * 256.f + fabsf(uz);
    float cost_v = fabsf(vx) * 65536.f + fabsf(vy) * 256.f + fabsf(vz);
    bool tfast = cost_u < cost_v;
    int ti = tfast ? (rl & 255) : (rl >> 8);
    int si = tfast ? (rl >> 8) : (rl & 255);

    float sdr = sdrp[0];
    float tx = trans[0], ty = trans[1], tz = trans[2];

    float sx = sdr * r0x + tx,  sy = sdr * r0y + ty,  sz = sdr * r0z + tz;
    float cxx = -sdr * r0x + tx, cxy = -sdr * r0y + ty, cxz = -sdr * r0z + tz;

    float tval = (float)(ti - 127) * 2.0f;
    float sval = (float)(si - 127) * 2.0f;

    float gx = tval * ux + sval * vx + cxx;
    float gy = tval * uy + sval * vy + cxy;
    float gz = tval * uz + sval * vz + cxz;

    float sdx = gx - sx + 1e-8f;
    float sdy = gy - sy + 1e-8f;
    float sdz = gz - sz + 1e-8f;

    float spx = spacing[0], spy = spacing[1], spz = spacing[2];
    float rdx = 1.0f / sdx, rdy = 1.0f / sdy, rdz = 1.0f / sdz;

    float a0x = palpha(0, spx, sx, rdx), a1x = palpha(NPLANE, spx, sx, rdx);
    float a0y = palpha(0, spy, sy, rdy), a1y = palpha(NPLANE, spy, sy, rdy);
    float a0z = palpha(0, spz, sz, rdz), a1z = palpha(NPLANE, spz, sz, rdz);

    float amin = fmaxf(fmaxf(fminf(a0x, a1x), fminf(a0y, a1y)), fminf(a0z, a1z));
    float amax = fminf(fminf(fmaxf(a0x, a1x), fmaxf(a0y, a1y)), fmaxf(a0z, a1z));

    float acc = 0.f;

    if (amax > amin) {
        float range = amax - amin;
        constexpr float inv = 1.0f / (float)TPR;
        float lo = fmaf(range, (float)part * inv, amin);
        float hi = (part == TPR - 1) ? INFINITY
                                     : fmaf(range, (float)(part + 1) * inv, amin);
        float end = fminf(hi, amax);

        int ix, iy, iz, dix, diy, diz;
        float nxx, nxy, nxz;

        #define SETUP(SP, SRC, SDD, RD, I, DI, NXT)                                \
        {                                                                          \
            float q = fmaf(lo, SDD, SRC) / (SP);                                   \
            q = fminf(fmaxf(q, -1.f), 257.f);                                      \
            if ((SDD) > 0.f) {                                                     \
                DI = 1;                                                            \
                I = (int)ceilf(q);                                                 \
                while (I > 0 && palpha(I - 1, SP, SRC, RD) >= lo) --I;             \
                while (I <= NPLANE && palpha(I, SP, SRC, RD) < lo) ++I;            \
                NXT = (I <= NPLANE) ? palpha(I, SP, SRC, RD) : INFINITY;           \
            } else {                                                               \
                DI = -1;                                                           \
                I = (int)floorf(q);                                                \
                while (I < NPLANE && palpha(I + 1, SP, SRC, RD) >= lo) ++I;        \
                while (I >= 0 && palpha(I, SP, SRC, RD) < lo) --I;                 \
                NXT = (I >= 0) ? palpha(I, SP, SRC, RD) : INFINITY;                \
            }                                                                      \
        }

        SETUP(spx, sx, sdx, rdx, ix, dix, nxx)
        SETUP(spy, sy, sdy, rdy, iy, diy, nxy)
        SETUP(spz, sz, sdz, rdz, iz, diz, nxz)
        #undef SETUP

        float cur = fminf(fminf(nxx, nxy), nxz);
        float ispx = 1.0f / spx, ispy = 1.0f / spy, ispz = 1.0f / spz;

        bool unit = (spx == 1.f) && (spy == 1.f) && (spz == 1.f);  // uniform
        if (unit)
            acc = trace_slice<true >(vol, cur, end, amax,
                (float)ix, (float)iy, (float)iz,
                (float)dix, (float)diy, (float)diz,
                nxx, nxy, nxz, spx, spy, spz, -sx, -sy, -sz,
                rdx, rdy, rdz, sdx, sdy, sdz, sx, sy, sz, ispx, ispy, ispz);
        else
            acc = trace_slice<false>(vol, cur, end, amax,
                (float)ix, (float)iy, (float)iz,
                (float)dix, (float)diy, (float)diz,
                nxx, nxy, nxz, spx, spy, spz, -sx, -sy, -sz,
                rdx, rdy, rdz, sdx, sdy, sdz, sx, sy, sz, ispx, ispy, ispz);
    }

    for (int off = TPR / 2; off > 0; off >>= 1)
        acc += __shfl_down(acc, off, TPR);

    if (part == 0) {
        float rl2 = sqrtf(sdx * sdx + sdy * sdy + sdz * sdz);
        out[ti * 256 + si] = acc * rl2;
    }
}

extern "C" void kernel_launch(void* const* d_in, const int* in_sizes, int n_in,
                              void* d_out, int out_size, void* d_ws, size_t ws_size,
                              hipStream_t stream) {
    const float* vol     = (const float*)d_in[0];
    const float* spacing = (const float*)d_in[1];
    const float* sdr     = (const float*)d_in[2];
    const float* rot     = (const float*)d_in[3];
    const float* trans   = (const float*)d_in[4];
    float* out = (float*)d_out;

    int total = 256 * 256 * TPR;   // 1,048,576 threads
    drr_kernel<<<total / 256, 256, 0, stream>>>(vol, spacing, sdr, rot, trans, out);
}